// Round 1
// 198.474 us; speedup vs baseline: 1.0428x; 1.0428x over previous
//
#include <hip/hip_runtime.h>

#define EMBED 768
#define NHEAD 12
#define HDIM 64
#define BATCH 8
#define SEQ 1024
#define ROWS (BATCH*SEQ)      // 8192
#define QKVN (3*EMBED)        // 2304
#define ATTN_SCALE 0.125f     // 1/sqrt(64)

typedef short s16x8 __attribute__((ext_vector_type(8)));
typedef short s16x4 __attribute__((ext_vector_type(4)));
typedef float f32x4 __attribute__((ext_vector_type(4)));

__device__ __forceinline__ float bf2f(unsigned short u) {
    union { unsigned int i; float f; } v; v.i = ((unsigned int)u) << 16; return v.f;
}
__device__ __forceinline__ unsigned short f2bf(float f) {
    unsigned int i = __builtin_bit_cast(unsigned int, f);
    i += 0x7FFFu + ((i >> 16) & 1u);   // RNE; finite values only
    return (unsigned short)(i >> 16);
}

// async global->LDS, 16 bytes per lane; LDS dest = wave-uniform base + lane*16
__device__ __forceinline__ void async16(short* lds, const unsigned short* g) {
    __builtin_amdgcn_global_load_lds(
        (const __attribute__((address_space(1))) unsigned int*)g,
        (__attribute__((address_space(3))) unsigned int*)lds,
        16, 0, 0);
}

__device__ __forceinline__ f32x4 mfma16(s16x4 a, s16x4 b, f32x4 c) {
#if __has_builtin(__builtin_amdgcn_mfma_f32_16x16x16bf16_1k)
    return __builtin_amdgcn_mfma_f32_16x16x16bf16_1k(a, b, c, 0, 0, 0);
#else
    asm volatile("v_mfma_f32_16x16x16_bf16 %0, %1, %2, %0" : "+v"(c) : "v"(a), "v"(b));
    return c;
#endif
}

// Fused prep.
// blk [0,432):   qkv_w fp32[768][2304] -> bf16 [2304][768]  (64x64 LDS tile transpose)
// blk [432,576): proj_w fp32[768][768] -> bf16 [768][768]
// blk [576,3648): hidden fp32 -> bf16 row-convert (8 elem/thread)
__global__ __launch_bounds__(256) void prep_k(
    const float* __restrict__ qkv_w, unsigned short* __restrict__ WqkvT,
    const float* __restrict__ proj_w, unsigned short* __restrict__ WprojT,
    const float* __restrict__ hidden, unsigned short* __restrict__ hiddenBf)
{
    __shared__ float tile[64][65];
    int blk = blockIdx.x;
    int t = threadIdx.x;
    if (blk < 576) {
        const float* in; unsigned short* outp; int K, N, tx, ty;
        if (blk < 432) { in = qkv_w; outp = WqkvT; K = EMBED; N = QKVN; tx = blk % 36; ty = blk / 36; }
        else { int b2 = blk - 432; in = proj_w; outp = WprojT; K = EMBED; N = EMBED; tx = b2 % 12; ty = b2 / 12; }
        int n0 = tx * 64, k0 = ty * 64;
        int c = t & 63, r0 = t >> 6;
        #pragma unroll
        for (int i = 0; i < 16; i++) {
            int r = r0 * 16 + i;
            tile[r][c] = in[(long long)(k0 + r) * N + n0 + c];   // coalesced 256B/row-group
        }
        __syncthreads();
        #pragma unroll
        for (int i = 0; i < 16; i++) {
            int nr = r0 * 16 + i;
            outp[(long long)(n0 + nr) * K + k0 + c] = f2bf(tile[c][nr]); // coalesced writes
        }
    } else {
        int tid = (blk - 576) * 256 + t;
        int base = tid * 8;
        float4 f0 = *(const float4*)&hidden[base];
        float4 f1 = *(const float4*)&hidden[base + 4];
        s16x8 a;
        a[0] = (short)f2bf(f0.x); a[1] = (short)f2bf(f0.y);
        a[2] = (short)f2bf(f0.z); a[3] = (short)f2bf(f0.w);
        a[4] = (short)f2bf(f1.x); a[5] = (short)f2bf(f1.y);
        a[6] = (short)f2bf(f1.z); a[7] = (short)f2bf(f1.w);
        *(s16x8*)&hiddenBf[base] = a;
    }
}

// m97-class GEMM: C[M][N] = A[M][K] @ Bt[N][K]^T + bias; A,Bt bf16; C fp32/bf16.
// tile 128x128, BK=32, 4 waves (wave: 64x64 via 4x4 mfma_16x16x32).
// LDS: unpadded 128x32 tiles, chunk-XOR swizzle on the *source* pointer
// -> global_load_lds writes AND ds_read_b128 fragment reads both conflict-free.
template <int OUT_F32>
__global__ __launch_bounds__(256) void gemm128(
    const unsigned short* __restrict__ A,
    const unsigned short* __restrict__ Bt,
    const float* __restrict__ bias,
    void* __restrict__ Cv,
    int M, int N, int K)
{
    __shared__ short As[128 * 32];
    __shared__ short Bs[128 * 32];
    int t = threadIdx.x, lane = t & 63, w = t >> 6;
    int quad = lane >> 4, low = lane & 15;
    int m0 = blockIdx.x * 128, n0 = blockIdx.y * 128;
    int wm = (w & 1) * 64, wn = (w >> 1) * 64;

    int ci0 = w * 128 + lane;
    int r0 = ci0 >> 2, c0 = (ci0 & 3) ^ ((r0 >> 1) & 3);
    int ci1 = ci0 + 64;
    int r1 = ci1 >> 2, c1 = (ci1 & 3) ^ ((r1 >> 1) & 3);
    const unsigned short* pa0 = A + (long long)(m0 + r0) * K + c0 * 8;
    const unsigned short* pa1 = A + (long long)(m0 + r1) * K + c1 * 8;
    const unsigned short* pb0 = Bt + (long long)(n0 + r0) * K + c0 * 8;
    const unsigned short* pb1 = Bt + (long long)(n0 + r1) * K + c1 * 8;
    short* la0 = As + (w * 128) * 8;
    short* la1 = As + (w * 128 + 64) * 8;
    short* lb0 = Bs + (w * 128) * 8;
    short* lb1 = Bs + (w * 128 + 64) * 8;

    f32x4 acc[4][4] = {};
    for (int k0 = 0; k0 < K; k0 += 32) {
        __syncthreads();
        async16(la0, pa0 + k0);
        async16(la1, pa1 + k0);
        async16(lb0, pb0 + k0);
        async16(lb1, pb1 + k0);
        __syncthreads();
        s16x8 af[4], bfr[4];
        #pragma unroll
        for (int i = 0; i < 4; i++) {
            int ra = wm + i * 16 + low;
            af[i] = *(const s16x8*)&As[ra * 32 + ((quad ^ ((ra >> 1) & 3)) * 8)];
            int rb = wn + i * 16 + low;
            bfr[i] = *(const s16x8*)&Bs[rb * 32 + ((quad ^ ((rb >> 1) & 3)) * 8)];
        }
        #pragma unroll
        for (int i = 0; i < 4; i++)
            #pragma unroll
            for (int j = 0; j < 4; j++)
                acc[i][j] = __builtin_amdgcn_mfma_f32_16x16x32_bf16(af[i], bfr[j], acc[i][j], 0, 0, 0);
    }
    #pragma unroll
    for (int i = 0; i < 4; i++)
        #pragma unroll
        for (int j = 0; j < 4; j++)
            #pragma unroll
            for (int r = 0; r < 4; r++) {
                int m = m0 + wm + i * 16 + quad * 4 + r;
                int n = n0 + wn + j * 16 + low;
                float v = acc[i][j][r] + bias[n];
                if (OUT_F32) ((float*)Cv)[(long long)m * N + n] = v;
                else ((unsigned short*)Cv)[(long long)m * N + n] = f2bf(v);
            }
}

// MFMA flash attention v4: fully in-register softmax via swapped QK^T.
//  - S^T = mfma_16x16x32(K_frag, Q_frag): lane(quad,low) holds S[q=low][kv=n*16+quad*4+r]
//    == exactly the A-fragment layout of mfma_16x16x16 (row=low, k=quad*4+i).
//  - P = exp(S*scale) packed in-register via v_cvt_pk_bf16_f32 -> PV uses K=16 MFMAs.
//    P never touches LDS; row-sum is a per-lane scalar.
//  - K staged via global_load_lds with chunk-XOR pre-swizzled source (conflict-free b128 reads).
//  - V^T staged as 4x4 lane-local subtiles -> 4x ds_write_b64/thread, stride 68 (bank floor).
//  - bh = blk % 96: all 8 q-chunks of one (b,h) on one XCD; 12 heads x 256KB KV fits its L2.
__global__ __launch_bounds__(256) void attn_k(
    const unsigned short* __restrict__ mixed,  // [8192][2304] : Q|K|V per row (bf16)
    unsigned short* __restrict__ ctx)          // [8192][768]
{
    __shared__ short Ks[64 * 64];      // K tile [kv][d], chunk-XOR swizzled, linear rows
    __shared__ short Vt[64 * 68];      // V^T tile [d][kv], kv padded 64->68
    int blk = blockIdx.x;
    int bh = blk % 96;                 // XCD-grouped: 96 == 0 (mod 8)
    int qc = blk / 96;
    int b = bh / NHEAD, h = bh - b * NHEAD;
    int t = threadIdx.x;
    int lane = t & 63, w = t >> 6;
    int quad = lane >> 4, low = lane & 15;
    long long rowbase = (long long)b * SEQ;
    int q0 = qc * 128 + w * 32;
    int hoff = h * HDIM;

    // Q fragments (B-operand of swapped QK^T; layout identical to A-frag): [qh][dhalf]
    s16x8 qf[2][2];
    #pragma unroll
    for (int qh = 0; qh < 2; qh++) {
        long long r = (rowbase + q0 + qh * 16 + low) * QKVN + hoff;
        qf[qh][0] = *(const s16x8*)&mixed[r + quad * 8];
        qf[qh][1] = *(const s16x8*)&mixed[r + 32 + quad * 8];
    }

    // K staging: slot = w*128 + lane (+64); row = slot>>3, phys chunk = slot&7.
    // LDS phys chunk c of row r holds global d-chunk (c ^ (r&7)); read applies same XOR.
    int s0 = w * 128 + lane;
    int kr0 = s0 >> 3, kc0 = s0 & 7;
    int kg = kc0 ^ (kr0 & 7);          // (kr0+8)&7 == kr0&7, so same for both slots
    const unsigned short* pk0 = mixed + (rowbase + kr0) * QKVN + EMBED + hoff + kg * 8;
    const unsigned short* pk1 = mixed + (rowbase + kr0 + 8) * QKVN + EMBED + hoff + kg * 8;
    short* lk0 = Ks + (w * 128) * 8;
    short* lk1 = Ks + (w * 128 + 64) * 8;

    // V staging: thread owns d = dblk*4..+3, kv rows rq*4..+3 (4x4 subtile transpose)
    int dblk = t & 15, rq = t >> 4;
    const unsigned short* pv = mixed + (rowbase + rq * 4) * QKVN + 2 * EMBED + hoff + dblk * 4;

    f32x4 o[2][4] = {};
    float lsum[2] = {0.f, 0.f};

    for (int kv0 = 0; kv0 < SEQ; kv0 += 64) {
        long long koff = (long long)kv0 * QKVN;
        __syncthreads();
        async16(lk0, pk0 + koff);
        async16(lk1, pk1 + koff);
        s16x4 v0 = *(const s16x4*)&pv[koff];
        s16x4 v1 = *(const s16x4*)&pv[koff + QKVN];
        s16x4 v2 = *(const s16x4*)&pv[koff + 2 * QKVN];
        s16x4 v3 = *(const s16x4*)&pv[koff + 3 * QKVN];
        #pragma unroll
        for (int k = 0; k < 4; k++) {
            s16x4 wv;
            wv[0] = v0[k]; wv[1] = v1[k]; wv[2] = v2[k]; wv[3] = v3[k];
            *(s16x4*)&Vt[(dblk * 4 + k) * 68 + rq * 4] = wv;
        }
        __syncthreads();

        // S^T: per kv-16 block n, sT[qh][n][r] = S[q0+qh*16+low][kv0+n*16+quad*4+r]
        f32x4 sT[2][4] = {};
        __builtin_amdgcn_s_setprio(1);
        #pragma unroll
        for (int n = 0; n < 4; n++) {
            int rr = n * 16 + low;
            int key = low & 7;
            s16x8 kf0 = *(const s16x8*)&Ks[rr * 64 + ((quad ^ key) * 8)];
            s16x8 kf1 = *(const s16x8*)&Ks[rr * 64 + (((quad + 4) ^ key) * 8)];
            sT[0][n] = __builtin_amdgcn_mfma_f32_16x16x32_bf16(kf0, qf[0][0], sT[0][n], 0, 0, 0);
            sT[0][n] = __builtin_amdgcn_mfma_f32_16x16x32_bf16(kf1, qf[0][1], sT[0][n], 0, 0, 0);
            sT[1][n] = __builtin_amdgcn_mfma_f32_16x16x32_bf16(kf0, qf[1][0], sT[1][n], 0, 0, 0);
            sT[1][n] = __builtin_amdgcn_mfma_f32_16x16x32_bf16(kf1, qf[1][1], sT[1][n], 0, 0, 0);
        }
        __builtin_amdgcn_s_setprio(0);

        // P = exp(S*scale): in-register, pack straight into x16 A-fragments
        s16x4 pf[2][4];
        #pragma unroll
        for (int qh = 0; qh < 2; qh++)
            #pragma unroll
            for (int n = 0; n < 4; n++) {
                float e0 = __expf(sT[qh][n][0] * ATTN_SCALE);
                float e1 = __expf(sT[qh][n][1] * ATTN_SCALE);
                float e2 = __expf(sT[qh][n][2] * ATTN_SCALE);
                float e3 = __expf(sT[qh][n][3] * ATTN_SCALE);
                lsum[qh] += (e0 + e1) + (e2 + e3);
                unsigned int w0, w1;
                asm("v_cvt_pk_bf16_f32 %0, %1, %2" : "=v"(w0) : "v"(e0), "v"(e1));
                asm("v_cvt_pk_bf16_f32 %0, %1, %2" : "=v"(w1) : "v"(e2), "v"(e3));
                union { unsigned int u[2]; s16x4 v; } pu;
                pu.u[0] = w0; pu.u[1] = w1;
                pf[qh][n] = pu.v;
            }

        // O += P @ V  (x16 MFMAs; V frag = contiguous b64 from V^T)
        __builtin_amdgcn_s_setprio(1);
        #pragma unroll
        for (int nt = 0; nt < 4; nt++) {
            int drow = nt * 16 + low;
            #pragma unroll
            for (int n = 0; n < 4; n++) {
                s16x4 vf = *(const s16x4*)&Vt[drow * 68 + n * 16 + quad * 4];
                o[0][nt] = mfma16(pf[0][n], vf, o[0][nt]);
                o[1][nt] = mfma16(pf[1][n], vf, o[1][nt]);
            }
        }
        __builtin_amdgcn_s_setprio(0);
    }

    // full row-sums: combine the 4 quad-partials for each q=low
    #pragma unroll
    for (int qh = 0; qh < 2; qh++) {
        lsum[qh] += __shfl_xor(lsum[qh], 16, 64);
        lsum[qh] += __shfl_xor(lsum[qh], 32, 64);
    }
    #pragma unroll
    for (int qh = 0; qh < 2; qh++)
        #pragma unroll
        for (int r = 0; r < 4; r++) {
            float inv = 1.0f / __shfl(lsum[qh], quad * 4 + r, 64);
            int q = q0 + qh * 16 + quad * 4 + r;
            #pragma unroll
            for (int nt = 0; nt < 4; nt++)
                ctx[(rowbase + q) * EMBED + hoff + nt * 16 + low] =
                    f2bf(o[qh][nt][r] * inv);
        }
}

extern "C" void kernel_launch(void* const* d_in, const int* in_sizes, int n_in,
                              void* d_out, int out_size, void* d_ws, size_t ws_size,
                              hipStream_t stream) {
    const float* hidden = (const float*)d_in[0];
    const float* qkv_w  = (const float*)d_in[1];
    const float* qkv_b  = (const float*)d_in[2];
    const float* proj_w = (const float*)d_in[3];
    const float* proj_b = (const float*)d_in[4];
    float* out = (float*)d_out;        // fp32 output

    char* ws = (char*)d_ws;
    // hiddenBf dead after QKV GEMM; ctx written only by attn -> alias (stream-serialized).
    unsigned short* hiddenBf = (unsigned short*)ws;                      // 8192x768  bf16
    unsigned short* ctx      = (unsigned short*)ws;                      // aliases hiddenBf
    unsigned short* WqkvT    = (unsigned short*)(ws + 12582912);         // 2304x768  bf16
    unsigned short* WprojT   = (unsigned short*)(ws + 16121856);         // 768x768   bf16
    unsigned short* mixed    = (unsigned short*)(ws + 17301504);         // 8192x2304 bf16

    prep_k<<<dim3(3648), 256, 0, stream>>>(qkv_w, WqkvT, proj_w, WprojT, hidden, hiddenBf);
    gemm128<0><<<dim3(ROWS / 128, QKVN / 128), 256, 0, stream>>>(
        hiddenBf, WqkvT, qkv_b, mixed, ROWS, QKVN, EMBED);
    attn_k<<<dim3(96 * 8), 256, 0, stream>>>(mixed, ctx);
    gemm128<1><<<dim3(ROWS / 128, EMBED / 128), 256, 0, stream>>>(
        ctx, WprojT, proj_b, out, ROWS, EMBED, EMBED);
}